// Round 1
// baseline (467.852 us; speedup 1.0000x reference)
//
#include <hip/hip_runtime.h>
#include <stdint.h>
#include <math.h>

// Problem constants (match reference setup_inputs)
#define IMGF   512.0f
#define A_N    49104
#define B_N    8
#define C_N    80
#define K_N    256
#define IOU_T  0.5f

// ---------------------------------------------------------------------------
// Kernel A: per-anchor max/argmax over 80 classes, sigmoid + threshold,
// emit order-preserving uint32 score key + int32 label.
// sigmoid is monotonic -> argmax/max over logits directly.
// ---------------------------------------------------------------------------
__global__ __launch_bounds__(256) void score_kernel(
    const float* __restrict__ logits,
    uint32_t* __restrict__ keys,
    int* __restrict__ labels,
    int total)
{
    int g = blockIdx.x * 256 + threadIdx.x;
    if (g >= total) return;
    const float4* p = (const float4*)(logits + (size_t)g * C_N);
    float m = -INFINITY;
    int lab = 0;
#pragma unroll
    for (int k = 0; k < C_N / 4; ++k) {
        float4 v = p[k];
        if (v.x > m) { m = v.x; lab = 4 * k + 0; }
        if (v.y > m) { m = v.y; lab = 4 * k + 1; }
        if (v.z > m) { m = v.z; lab = 4 * k + 2; }
        if (v.w > m) { m = v.w; lab = 4 * k + 3; }
    }
    float s = 1.0f / (1.0f + expf(-m));
    if (!(s > 0.01f)) s = 0.0f;              // reference: where(s > 0.01, s, 0)
    keys[g]   = __float_as_uint(s);          // s >= 0 -> bits are order-preserving
    labels[g] = lab;
}

// ---------------------------------------------------------------------------
// Kernel B: one block (256 threads) per batch.
//   1) 4-round radix select over byte planes -> exact 256th-largest key T
//   2) compact keys > T, plus smallest-index ties at == T (lax.top_k stable)
//   3) bitonic sort 256 by (key desc, index asc)
//   4) decode the 256 selected boxes (fp-contract off to match numpy)
//   5) 256x256 suppression bitmask + serial greedy scan == reference NMS
//   6) write dets [B,K,5], labels [B,K], keep [B,K] as float32
// ---------------------------------------------------------------------------
__global__ __launch_bounds__(256) void topk_nms_kernel(
    const uint32_t* __restrict__ keys,
    const int* __restrict__ labels,
    const float* __restrict__ regs,
    const float* __restrict__ anchors,
    float* __restrict__ out)
{
    const int b   = blockIdx.x;
    const int tid = threadIdx.x;
    const uint32_t* kb = keys + (size_t)b * A_N;

    __shared__ uint32_t hist[256];
    __shared__ uint32_t sh_prefix, sh_pmask;
    __shared__ int sh_k;
    __shared__ int n_gt, n_eq;
    __shared__ unsigned long long comb[K_N];
    __shared__ int eq_idx[1024];
    __shared__ float4 sbox[K_N];
    __shared__ float  sscore[K_N];
    __shared__ int    slab[K_N];
    __shared__ unsigned long long supr[K_N][4];
    __shared__ unsigned long long keepw[4];

    if (tid == 0) { sh_prefix = 0u; sh_pmask = 0u; sh_k = K_N; }
    __syncthreads();

    // ---- Phase 1: radix select (find exact key value of rank-256) ----
    for (int shift = 24; shift >= 0; shift -= 8) {
        hist[tid] = 0;
        __syncthreads();
        uint32_t prefix = sh_prefix, pmask = sh_pmask;
        for (int i = tid; i < A_N; i += 256) {
            uint32_t key = kb[i];
            if ((key & pmask) == prefix)
                atomicAdd(&hist[(key >> shift) & 255u], 1u);
        }
        __syncthreads();
        if (tid == 0) {
            int k = sh_k;
            uint32_t cum = 0;
            for (int bin = 255; bin >= 0; --bin) {
                uint32_t c = hist[bin];
                if (cum + c >= (uint32_t)k) {
                    sh_k = k - (int)cum;
                    sh_prefix = prefix | ((uint32_t)bin << shift);
                    sh_pmask  = pmask  | (0xFFu << shift);
                    break;
                }
                cum += c;
            }
        }
        __syncthreads();
    }
    const uint32_t T = sh_prefix;
    const int rem = sh_k;               // how many ties at == T we still need
    if (tid == 0) { n_gt = 0; n_eq = 0; }
    __syncthreads();

    // ---- Phase 2: compact ----
    for (int i = tid; i < A_N; i += 256) {
        uint32_t key = kb[i];
        if (key > T) {
            int p = atomicAdd(&n_gt, 1);
            // guaranteed p < 256 by rank construction
            comb[p] = ((unsigned long long)key << 32)
                    | (unsigned long long)(0xFFFFFFFFu - (uint32_t)i);
        } else if (key == T) {
            int p = atomicAdd(&n_eq, 1);
            if (p < 1024) eq_idx[p] = i;
        }
    }
    __syncthreads();
    if (tid == 0) {
        int ng = n_gt;
        int ne = n_eq; if (ne > 1024) ne = 1024;
        // pick the `rem` smallest indices among ties (stable top_k semantics)
        for (int t = 0; t < rem; ++t) {
            int best = 0x7FFFFFFF, bp = -1;
            for (int q = 0; q < ne; ++q) {
                int v = eq_idx[q];
                if (v < best) { best = v; bp = q; }
            }
            if (bp >= 0) {
                eq_idx[bp] = 0x7FFFFFFF;
                comb[ng + t] = ((unsigned long long)T << 32)
                             | (unsigned long long)(0xFFFFFFFFu - (uint32_t)best);
            } else {
                comb[ng + t] = 0ull;  // unreachable (rank invariant)
            }
        }
    }
    __syncthreads();

    // ---- Phase 3: bitonic sort descending (key desc, index asc) ----
    for (int k = 2; k <= K_N; k <<= 1) {
        for (int j = k >> 1; j > 0; j >>= 1) {
            int ixj = tid ^ j;
            if (ixj > tid) {
                unsigned long long a = comb[tid], c = comb[ixj];
                bool up = ((tid & k) == 0);
                bool sw = up ? (a < c) : (a > c);   // inverted -> descending
                if (sw) { comb[tid] = c; comb[ixj] = a; }
            }
            __syncthreads();
        }
    }

    // ---- Phase 4: decode selected boxes ----
    {
#pragma clang fp contract(off)
        unsigned long long cv = comb[tid];
        uint32_t key = (uint32_t)(cv >> 32);
        uint32_t ai  = 0xFFFFFFFFu - (uint32_t)cv;
        if (ai >= (uint32_t)A_N) ai = 0;   // safety (unreachable)
        int a = (int)ai;
        float s = __uint_as_float(key);
        sscore[tid] = s;
        slab[tid]   = labels[(size_t)b * A_N + a];

        float ax0 = anchors[4 * a + 0], ay0 = anchors[4 * a + 1];
        float ax1 = anchors[4 * a + 2], ay1 = anchors[4 * a + 3];
        float aw = ax1 - ax0, ah = ay1 - ay0;
        float acx = ax0 + 0.5f * aw, acy = ay0 + 0.5f * ah;
        const float* r = regs + ((size_t)b * A_N + a) * 4;
        float dx = r[0], dy = r[1], dw = r[2], dh = r[3];
        float cx = acx + dx * aw;
        float cy = acy + dy * ah;
        dw = fminf(fmaxf(dw, -4.0f), 4.0f);
        dh = fminf(fmaxf(dh, -4.0f), 4.0f);
        float w = aw * expf(dw);
        float h = ah * expf(dh);
        float x0 = cx - 0.5f * w, y0 = cy - 0.5f * h;
        float x1 = cx + 0.5f * w, y1 = cy + 0.5f * h;
        x0 = fminf(fmaxf(x0, 0.0f), IMGF);
        y0 = fminf(fmaxf(y0, 0.0f), IMGF);
        x1 = fminf(fmaxf(x1, 0.0f), IMGF);
        y1 = fminf(fmaxf(y1, 0.0f), IMGF);
        sbox[tid] = make_float4(x0, y0, x1, y1);
    }
    __syncthreads();

    // ---- Phase 5: suppression bitmask + greedy serial scan ----
    {
#pragma clang fp contract(off)
        float4 bi = sbox[tid];
        float areai = fmaxf(bi.z - bi.x, 0.0f) * fmaxf(bi.w - bi.y, 0.0f);
        unsigned long long m0 = 0, m1 = 0, m2 = 0, m3 = 0;
        for (int j = tid + 1; j < K_N; ++j) {
            float4 bj = sbox[j];
            float areaj = fmaxf(bj.z - bj.x, 0.0f) * fmaxf(bj.w - bj.y, 0.0f);
            float lx = fmaxf(bi.x, bj.x), ly = fmaxf(bi.y, bj.y);
            float rx = fminf(bi.z, bj.z), ry = fminf(bi.w, bj.w);
            float iw = fmaxf(rx - lx, 0.0f), ih = fmaxf(ry - ly, 0.0f);
            float inter = iw * ih;
            float uni = areai + areaj - inter;
            float iou = inter / fmaxf(uni, 1e-8f);
            if (iou > IOU_T) {
                unsigned long long bit = 1ull << (j & 63);
                switch (j >> 6) {
                    case 0: m0 |= bit; break;
                    case 1: m1 |= bit; break;
                    case 2: m2 |= bit; break;
                    default: m3 |= bit; break;
                }
            }
        }
        supr[tid][0] = m0; supr[tid][1] = m1; supr[tid][2] = m2; supr[tid][3] = m3;
    }
    unsigned long long ball = __ballot(sscore[tid] > 0.0f);  // keep0 = s > 0
    if ((tid & 63) == 0) keepw[tid >> 6] = ball;
    __syncthreads();
    if (tid == 0) {
        unsigned long long k0 = keepw[0], k1 = keepw[1], k2 = keepw[2], k3 = keepw[3];
        for (int i = 0; i < K_N; ++i) {
            unsigned long long kw = (i < 64) ? k0 : (i < 128) ? k1 : (i < 192) ? k2 : k3;
            if ((kw >> (i & 63)) & 1ull) {
                k0 &= ~supr[i][0]; k1 &= ~supr[i][1];
                k2 &= ~supr[i][2]; k3 &= ~supr[i][3];
            }
        }
        keepw[0] = k0; keepw[1] = k1; keepw[2] = k2; keepw[3] = k3;
    }
    __syncthreads();

    // ---- Phase 6: outputs (float32): dets [B,K,5] ++ labels [B,K] ++ keep [B,K]
    {
        float keepf = ((keepw[tid >> 6] >> (tid & 63)) & 1ull) ? 1.0f : 0.0f;
        float4 bx = sbox[tid];
        float s = sscore[tid];
        float* det = out + ((size_t)b * K_N + tid) * 5;
        det[0] = bx.x * keepf;
        det[1] = bx.y * keepf;
        det[2] = bx.z * keepf;
        det[3] = bx.w * keepf;
        det[4] = s * keepf;
        out[(size_t)B_N * K_N * 5 + (size_t)b * K_N + tid] = (float)slab[tid];
        out[(size_t)B_N * K_N * 5 + (size_t)B_N * K_N + (size_t)b * K_N + tid] = keepf;
    }
}

extern "C" void kernel_launch(void* const* d_in, const int* in_sizes, int n_in,
                              void* d_out, int out_size, void* d_ws, size_t ws_size,
                              hipStream_t stream)
{
    const float* logits  = (const float*)d_in[0];   // [B,A,C] fp32
    const float* regs    = (const float*)d_in[1];   // [B,A,4] fp32
    const float* anchors = (const float*)d_in[2];   // [A,4]   fp32
    float* out = (float*)d_out;

    uint32_t* keys = (uint32_t*)d_ws;
    int* labels = (int*)((char*)d_ws + (size_t)B_N * A_N * sizeof(uint32_t));

    int total = B_N * A_N;
    score_kernel<<<(total + 255) / 256, 256, 0, stream>>>(logits, keys, labels, total);
    topk_nms_kernel<<<B_N, 256, 0, stream>>>(keys, labels, regs, anchors, out);
}

// Round 2
// 438.061 us; speedup vs baseline: 1.0680x; 1.0680x over previous
//
#include <hip/hip_runtime.h>
#include <stdint.h>
#include <math.h>

// Problem constants (match reference setup_inputs)
#define IMGF   512.0f
#define A_N    49104
#define B_N    8
#define C_N    80
#define K_N    256
#define IOU_T  0.5f
#define NBIN   32768          // histogram bins over key >> 16
#define CAP    4096           // candidate capacity (bins >= threshold bin)

// ---------------------------------------------------------------------------
// Kernel A: 4 lanes per anchor. Each lane loads 5 float4s at lane-consecutive
// offsets (fully-consumed 64B lines per instruction -> no L1-retention
// dependence). Packed (flipped-logit || ~label) u64 max via 2 shuffles gives
// max+first-argmax (sigmoid monotonic). Lane j==0 computes sigmoid, applies
// threshold, writes order-preserving key + label, and bumps the per-batch
// 32768-bin global histogram (key>>16).
// ---------------------------------------------------------------------------
__global__ __launch_bounds__(256) void score_kernel(
    const float* __restrict__ logits,
    uint32_t* __restrict__ keys,
    int* __restrict__ labels,
    uint32_t* __restrict__ hist)
{
    const int tid  = threadIdx.x;
    const int wave = tid >> 6, lane = tid & 63;
    const int grp  = lane >> 2, j = lane & 3;
    const int g = blockIdx.x * 64 + wave * 16 + grp;   // anchor row (flat B*A)
    if (g >= B_N * A_N) return;                        // grid is exact; safety

    const float4* p = (const float4*)(logits + (size_t)g * C_N);
    unsigned long long best = 0ull;
#pragma unroll
    for (int k = 0; k < 5; ++k) {
        float4 v = p[j + 4 * k];
        const int bl = (j + 4 * k) * 4;
        float vals[4] = { v.x, v.y, v.z, v.w };
#pragma unroll
        for (int q = 0; q < 4; ++q) {
            uint32_t bbits = __float_as_uint(vals[q]);
            // order-preserving flip for signed floats
            uint32_t u = bbits ^ (0x80000000u | (uint32_t)((int32_t)bbits >> 31));
            unsigned long long pk = ((unsigned long long)u << 32)
                                  | (uint32_t)(~(uint32_t)(bl + q));
            if (pk > best) best = pk;
        }
    }
    {
        unsigned long long o1 = __shfl_xor(best, 1, 64);
        if (o1 > best) best = o1;
        unsigned long long o2 = __shfl_xor(best, 2, 64);
        if (o2 > best) best = o2;
    }
    if (j == 0) {
        uint32_t u  = (uint32_t)(best >> 32);
        uint32_t mb = (u & 0x80000000u) ? (u ^ 0x80000000u) : ~u;  // unflip
        float m = __uint_as_float(mb);
        float s = 1.0f / (1.0f + expf(-m));
        if (!(s > 0.01f)) s = 0.0f;            // reference: where(s > thr, s, 0)
        uint32_t key = __float_as_uint(s);     // s >= 0 -> bits order-preserving
        keys[g]   = key;
        labels[g] = (int)~((uint32_t)best);    // recover label
        int batch = g / A_N;
        atomicAdd(&hist[batch * NBIN + (key >> 16)], 1u);
    }
}

// ---------------------------------------------------------------------------
// Kernel B: one block (256 threads) per batch.
//   1) parallel suffix-scan of the 32768-bin histogram -> exact threshold
//      bin T15 such that count(bins > T15) < 256 <= count(bins >= T15)
//   2) compact all keys with (key>>16) >= T15 (~400-600 candidates)
//   3) bitonic sort by (key desc, idx asc)  == stable lax.top_k order
//   4) decode top-256 boxes (fp-contract off to match numpy)
//   5) 256x256 suppression bitmask + serial greedy scan == reference NMS
//   6) write dets [B,K,5] ++ labels [B,K] ++ keep [B,K] as float32
// ---------------------------------------------------------------------------
__global__ __launch_bounds__(256) void topk_nms_kernel(
    const uint32_t* __restrict__ keys,
    const int* __restrict__ labels,
    const float* __restrict__ regs,
    const float* __restrict__ anchors,
    const uint32_t* __restrict__ hist,
    float* __restrict__ out)
{
    const int b   = blockIdx.x;
    const int tid = threadIdx.x;
    const uint32_t* kb = keys + (size_t)b * A_N;
    const uint32_t* hb = hist + (size_t)b * NBIN;

    __shared__ unsigned long long cand[CAP];
    __shared__ int ssum[256];
    __shared__ int sh_T15, sh_nc;
    __shared__ float4 sbox[K_N];
    __shared__ float  sscore[K_N];
    __shared__ int    slab[K_N];
    __shared__ unsigned long long supr[K_N][4];
    __shared__ unsigned long long keepw[4];

    // ---- Phase 1: find threshold bin T15 ----
    const int SEG = NBIN / 256;          // 128 bins per thread
    const int lo  = tid * SEG;
    int seg = 0;
    for (int q = 0; q < SEG; ++q) seg += (int)hb[lo + q];
    ssum[tid] = seg;
    __syncthreads();
    for (int off = 1; off < 256; off <<= 1) {   // inclusive suffix sum
        int v = (tid + off < 256) ? ssum[tid + off] : 0;
        __syncthreads();
        ssum[tid] += v;
        __syncthreads();
    }
    int above = ssum[tid] - seg;         // keys in strictly-higher segments
    if (above < K_N && above + seg >= K_N) {   // exactly one thread true
        int cum = above;
        for (int bin = lo + SEG - 1; bin >= lo; --bin) {
            int c = (int)hb[bin];
            if (cum + c >= K_N) { sh_T15 = bin; break; }
            cum += c;
        }
    }
    if (tid == 0) sh_nc = 0;
    __syncthreads();
    const uint32_t T15 = (uint32_t)sh_T15;

    // ---- Phase 2: compact candidates (bins >= T15) ----
    for (int i = tid; i < A_N; i += 256) {
        uint32_t key = kb[i];
        if ((key >> 16) >= T15) {
            int p = atomicAdd(&sh_nc, 1);
            if (p < CAP)
                cand[p] = ((unsigned long long)key << 32)
                        | (unsigned long long)(0xFFFFFFFFu - (uint32_t)i);
        }
    }
    __syncthreads();
    int nc = sh_nc; if (nc > CAP) nc = CAP;
    int P = 256; while (P < nc) P <<= 1;       // pad to pow2 (<= CAP)
    for (int i = nc + tid; i < P; i += 256) cand[i] = 0ull;
    __syncthreads();

    // ---- Phase 3: bitonic sort descending by (key desc, idx asc) ----
    for (int k = 2; k <= P; k <<= 1) {
        for (int jj = k >> 1; jj > 0; jj >>= 1) {
            for (int i = tid; i < P; i += 256) {
                int ixj = i ^ jj;
                if (ixj > i) {
                    unsigned long long a = cand[i], c = cand[ixj];
                    bool up = ((i & k) == 0);
                    if (up ? (a < c) : (a > c)) { cand[i] = c; cand[ixj] = a; }
                }
            }
            __syncthreads();
        }
    }

    // ---- Phase 4: decode top-256 boxes ----
    {
#pragma clang fp contract(off)
        unsigned long long cv = cand[tid];
        uint32_t key = (uint32_t)(cv >> 32);
        uint32_t ai  = 0xFFFFFFFFu - (uint32_t)cv;
        if (ai >= (uint32_t)A_N) ai = 0;   // safety (pad entries: unreachable)
        int a = (int)ai;
        float s = __uint_as_float(key);
        sscore[tid] = s;
        slab[tid]   = labels[(size_t)b * A_N + a];

        float ax0 = anchors[4 * a + 0], ay0 = anchors[4 * a + 1];
        float ax1 = anchors[4 * a + 2], ay1 = anchors[4 * a + 3];
        float aw = ax1 - ax0, ah = ay1 - ay0;
        float acx = ax0 + 0.5f * aw, acy = ay0 + 0.5f * ah;
        const float* r = regs + ((size_t)b * A_N + a) * 4;
        float dx = r[0], dy = r[1], dw = r[2], dh = r[3];
        float cx = acx + dx * aw;
        float cy = acy + dy * ah;
        dw = fminf(fmaxf(dw, -4.0f), 4.0f);
        dh = fminf(fmaxf(dh, -4.0f), 4.0f);
        float w = aw * expf(dw);
        float h = ah * expf(dh);
        float x0 = cx - 0.5f * w, y0 = cy - 0.5f * h;
        float x1 = cx + 0.5f * w, y1 = cy + 0.5f * h;
        x0 = fminf(fmaxf(x0, 0.0f), IMGF);
        y0 = fminf(fmaxf(y0, 0.0f), IMGF);
        x1 = fminf(fmaxf(x1, 0.0f), IMGF);
        y1 = fminf(fmaxf(y1, 0.0f), IMGF);
        sbox[tid] = make_float4(x0, y0, x1, y1);
    }
    __syncthreads();

    // ---- Phase 5: suppression bitmask + greedy serial scan ----
    {
#pragma clang fp contract(off)
        float4 bi = sbox[tid];
        float areai = fmaxf(bi.z - bi.x, 0.0f) * fmaxf(bi.w - bi.y, 0.0f);
        unsigned long long m0 = 0, m1 = 0, m2 = 0, m3 = 0;
        for (int jx = tid + 1; jx < K_N; ++jx) {
            float4 bj = sbox[jx];
            float areaj = fmaxf(bj.z - bj.x, 0.0f) * fmaxf(bj.w - bj.y, 0.0f);
            float lx = fmaxf(bi.x, bj.x), ly = fmaxf(bi.y, bj.y);
            float rx = fminf(bi.z, bj.z), ry = fminf(bi.w, bj.w);
            float iw = fmaxf(rx - lx, 0.0f), ih = fmaxf(ry - ly, 0.0f);
            float inter = iw * ih;
            float uni = areai + areaj - inter;
            float iou = inter / fmaxf(uni, 1e-8f);
            if (iou > IOU_T) {
                unsigned long long bit = 1ull << (jx & 63);
                switch (jx >> 6) {
                    case 0: m0 |= bit; break;
                    case 1: m1 |= bit; break;
                    case 2: m2 |= bit; break;
                    default: m3 |= bit; break;
                }
            }
        }
        supr[tid][0] = m0; supr[tid][1] = m1; supr[tid][2] = m2; supr[tid][3] = m3;
    }
    unsigned long long ball = __ballot(sscore[tid] > 0.0f);  // keep0 = s > 0
    if ((tid & 63) == 0) keepw[tid >> 6] = ball;
    __syncthreads();
    if (tid == 0) {
        unsigned long long k0 = keepw[0], k1 = keepw[1], k2 = keepw[2], k3 = keepw[3];
        for (int i = 0; i < K_N; ++i) {
            unsigned long long kw = (i < 64) ? k0 : (i < 128) ? k1 : (i < 192) ? k2 : k3;
            if ((kw >> (i & 63)) & 1ull) {
                k0 &= ~supr[i][0]; k1 &= ~supr[i][1];
                k2 &= ~supr[i][2]; k3 &= ~supr[i][3];
            }
        }
        keepw[0] = k0; keepw[1] = k1; keepw[2] = k2; keepw[3] = k3;
    }
    __syncthreads();

    // ---- Phase 6: outputs: dets [B,K,5] ++ labels [B,K] ++ keep [B,K] ----
    {
        float keepf = ((keepw[tid >> 6] >> (tid & 63)) & 1ull) ? 1.0f : 0.0f;
        float4 bx = sbox[tid];
        float s = sscore[tid];
        float* det = out + ((size_t)b * K_N + tid) * 5;
        det[0] = bx.x * keepf;
        det[1] = bx.y * keepf;
        det[2] = bx.z * keepf;
        det[3] = bx.w * keepf;
        det[4] = s * keepf;
        out[(size_t)B_N * K_N * 5 + (size_t)b * K_N + tid] = (float)slab[tid];
        out[(size_t)B_N * K_N * 5 + (size_t)B_N * K_N + (size_t)b * K_N + tid] = keepf;
    }
}

extern "C" void kernel_launch(void* const* d_in, const int* in_sizes, int n_in,
                              void* d_out, int out_size, void* d_ws, size_t ws_size,
                              hipStream_t stream)
{
    const float* logits  = (const float*)d_in[0];   // [B,A,C] fp32
    const float* regs    = (const float*)d_in[1];   // [B,A,4] fp32
    const float* anchors = (const float*)d_in[2];   // [A,4]   fp32
    float* out = (float*)d_out;

    uint32_t* keys   = (uint32_t*)d_ws;
    int*      labels = (int*)(keys + (size_t)B_N * A_N);
    uint32_t* hist   = (uint32_t*)(labels + (size_t)B_N * A_N);

    hipMemsetAsync(hist, 0, (size_t)B_N * NBIN * sizeof(uint32_t), stream);

    const int total = B_N * A_N;                 // 392832 = 6138 * 64
    score_kernel<<<total / 64, 256, 0, stream>>>(logits, keys, labels, hist);
    topk_nms_kernel<<<B_N, 256, 0, stream>>>(keys, labels, regs, anchors, hist, out);
}

// Round 3
// 282.290 us; speedup vs baseline: 1.6573x; 1.5518x over previous
//
#include <hip/hip_runtime.h>
#include <stdint.h>
#include <math.h>

// Problem constants (match reference setup_inputs)
#define IMGF   512.0f
#define A_N    49104
#define B_N    8
#define C_N    80
#define K_N    256
#define IOU_T  0.5f
#define NBIN   4096      // bin = key >> 18; keys in [0, 0x3F800000] -> bin <= 4064
#define SHIFT  18
#define CAP    4096      // per-batch candidate capacity

// ---------------------------------------------------------------------------
// Kernel A: 4 lanes per anchor, 5 float4 loads each (fully-consumed 64B lines
// per instruction). Packed (flipped-logit || ~label) u64 max via 2 shuffles.
// Lane j==0 writes order-preserving score key + label. NO atomics.
// ---------------------------------------------------------------------------
__global__ __launch_bounds__(256) void score_kernel(
    const float* __restrict__ logits,
    uint32_t* __restrict__ keys,
    int* __restrict__ labels)
{
    const int tid  = threadIdx.x;
    const int wave = tid >> 6, lane = tid & 63;
    const int grp  = lane >> 2, j = lane & 3;
    const int g = blockIdx.x * 64 + wave * 16 + grp;   // anchor row (flat B*A)
    if (g >= B_N * A_N) return;

    const float4* p = (const float4*)(logits + (size_t)g * C_N);
    unsigned long long best = 0ull;
#pragma unroll
    for (int k = 0; k < 5; ++k) {
        float4 v = p[j + 4 * k];
        const int bl = (j + 4 * k) * 4;
        float vals[4] = { v.x, v.y, v.z, v.w };
#pragma unroll
        for (int q = 0; q < 4; ++q) {
            uint32_t bbits = __float_as_uint(vals[q]);
            uint32_t u = bbits ^ (0x80000000u | (uint32_t)((int32_t)bbits >> 31));
            unsigned long long pk = ((unsigned long long)u << 32)
                                  | (uint32_t)(~(uint32_t)(bl + q));
            if (pk > best) best = pk;
        }
    }
    {
        unsigned long long o1 = __shfl_xor(best, 1, 64);
        if (o1 > best) best = o1;
        unsigned long long o2 = __shfl_xor(best, 2, 64);
        if (o2 > best) best = o2;
    }
    if (j == 0) {
        uint32_t u  = (uint32_t)(best >> 32);
        uint32_t mb = (u & 0x80000000u) ? (u ^ 0x80000000u) : ~u;  // unflip
        float m = __uint_as_float(mb);
        float s = 1.0f / (1.0f + expf(-m));
        if (!(s > 0.01f)) s = 0.0f;
        keys[g]   = __float_as_uint(s);
        labels[g] = (int)~((uint32_t)best);
    }
}

// ---------------------------------------------------------------------------
// Kernel H: per-batch histogram with LDS privatization.
// grid = {16, B}. Each block: 3069 keys -> 4096-bin LDS hist -> flush nonzero
// bins with global atomicAdd (chains <= 16 per address).
// ---------------------------------------------------------------------------
__global__ __launch_bounds__(256) void hist_kernel(
    const uint32_t* __restrict__ keys,
    uint32_t* __restrict__ hist)
{
    const int b   = blockIdx.y;
    const int tid = threadIdx.x;
    __shared__ uint32_t lh[NBIN];
    for (int i = tid; i < NBIN; i += 256) lh[i] = 0;
    __syncthreads();
    const int chunk = A_N / 16;                     // 3069 (exact)
    const uint32_t* kb = keys + (size_t)b * A_N + (size_t)blockIdx.x * chunk;
    for (int i = tid; i < chunk; i += 256)
        atomicAdd(&lh[kb[i] >> SHIFT], 1u);
    __syncthreads();
    uint32_t* hb = hist + (size_t)b * NBIN;
    for (int i = tid; i < NBIN; i += 256) {
        uint32_t c = lh[i];
        if (c) atomicAdd(&hb[i], c);
    }
}

// ---------------------------------------------------------------------------
// Kernel C: threshold + compact. grid = {48, B}.
// Each block: suffix-scan hist -> exact threshold bin T (count(>T) < 256 <=
// count(>=T)); compact its 1023-key chunk (bin >= T) into LDS; ONE global
// reservation atomic; coalesced write to per-batch candidate list.
// ---------------------------------------------------------------------------
__global__ __launch_bounds__(256) void compact_kernel(
    const uint32_t* __restrict__ keys,
    const uint32_t* __restrict__ hist,
    unsigned long long* __restrict__ cand,    // [B][CAP]
    uint32_t* __restrict__ counts)            // [B]
{
    const int b   = blockIdx.y;
    const int tid = threadIdx.x;
    __shared__ int ssum[256];
    __shared__ int sh_T;
    __shared__ int lcnt;
    __shared__ uint32_t lbase;
    __shared__ unsigned long long lbuf[1024];

    // ---- threshold bin from histogram ----
    const uint32_t* hb = hist + (size_t)b * NBIN;
    const int SEG = NBIN / 256;                 // 16 bins per thread
    const int lo  = tid * SEG;
    int seg = 0;
    for (int q = 0; q < SEG; ++q) seg += (int)hb[lo + q];
    ssum[tid] = seg;
    __syncthreads();
    for (int off = 1; off < 256; off <<= 1) {   // inclusive suffix sum
        int v = (tid + off < 256) ? ssum[tid + off] : 0;
        __syncthreads();
        ssum[tid] += v;
        __syncthreads();
    }
    int above = ssum[tid] - seg;                // keys in strictly-higher segs
    if (above < K_N && above + seg >= K_N) {    // exactly one thread true
        int cum = above;
        for (int bin = lo + SEG - 1; bin >= lo; --bin) {
            int c = (int)hb[bin];
            if (cum + c >= K_N) { sh_T = bin; break; }
            cum += c;
        }
    }
    if (tid == 0) lcnt = 0;
    __syncthreads();
    const uint32_t T = (uint32_t)sh_T;

    // ---- compact this block's chunk ----
    const int chunk = A_N / 48;                 // 1023 (exact)
    const int base  = blockIdx.x * chunk;
    const uint32_t* kb = keys + (size_t)b * A_N;
    for (int i = tid; i < chunk; i += 256) {
        int idx = base + i;
        uint32_t key = kb[idx];
        if ((key >> SHIFT) >= T) {
            int p = atomicAdd(&lcnt, 1);        // p < 1024 by chunk size
            lbuf[p] = ((unsigned long long)key << 32)
                    | (unsigned long long)(0xFFFFFFFFu - (uint32_t)idx);
        }
    }
    __syncthreads();
    int n = lcnt;
    if (tid == 0) lbase = atomicAdd(&counts[b], (uint32_t)n);  // 1 atomic/block
    __syncthreads();
    uint32_t gb = lbase;
    for (int i = tid; i < n; i += 256) {
        uint32_t pos = gb + (uint32_t)i;
        if (pos < CAP) cand[(size_t)b * CAP + pos] = lbuf[i];
    }
}

// ---------------------------------------------------------------------------
// Kernel S: one block per batch. Load candidates, pad to pow2, bitonic sort by
// (key desc, idx asc) == stable lax.top_k, decode top-256, NMS, write outputs.
// ---------------------------------------------------------------------------
__global__ __launch_bounds__(256) void sort_nms_kernel(
    const unsigned long long* __restrict__ cand_g,
    const uint32_t* __restrict__ counts,
    const int* __restrict__ labels,
    const float* __restrict__ regs,
    const float* __restrict__ anchors,
    float* __restrict__ out)
{
    const int b   = blockIdx.x;
    const int tid = threadIdx.x;

    __shared__ unsigned long long cand[CAP];
    __shared__ float4 sbox[K_N];
    __shared__ float  sscore[K_N];
    __shared__ int    slab[K_N];
    __shared__ unsigned long long supr[K_N][4];
    __shared__ unsigned long long keepw[4];

    int nc = (int)counts[b]; if (nc > CAP) nc = CAP;
    for (int i = tid; i < nc; i += 256) cand[i] = cand_g[(size_t)b * CAP + i];
    int P = 256; while (P < nc) P <<= 1;
    for (int i = nc + tid; i < P; i += 256) cand[i] = 0ull;
    __syncthreads();

    // ---- bitonic sort descending by (key desc, idx asc) ----
    for (int k = 2; k <= P; k <<= 1) {
        for (int jj = k >> 1; jj > 0; jj >>= 1) {
            for (int i = tid; i < P; i += 256) {
                int ixj = i ^ jj;
                if (ixj > i) {
                    unsigned long long a = cand[i], c = cand[ixj];
                    bool up = ((i & k) == 0);
                    if (up ? (a < c) : (a > c)) { cand[i] = c; cand[ixj] = a; }
                }
            }
            __syncthreads();
        }
    }

    // ---- decode top-256 boxes ----
    {
#pragma clang fp contract(off)
        unsigned long long cv = cand[tid];
        uint32_t key = (uint32_t)(cv >> 32);
        uint32_t ai  = 0xFFFFFFFFu - (uint32_t)cv;
        if (ai >= (uint32_t)A_N) ai = 0;   // pad entries (score 0, unkept)
        int a = (int)ai;
        float s = __uint_as_float(key);
        sscore[tid] = s;
        slab[tid]   = labels[(size_t)b * A_N + a];

        float ax0 = anchors[4 * a + 0], ay0 = anchors[4 * a + 1];
        float ax1 = anchors[4 * a + 2], ay1 = anchors[4 * a + 3];
        float aw = ax1 - ax0, ah = ay1 - ay0;
        float acx = ax0 + 0.5f * aw, acy = ay0 + 0.5f * ah;
        const float* r = regs + ((size_t)b * A_N + a) * 4;
        float dx = r[0], dy = r[1], dw = r[2], dh = r[3];
        float cx = acx + dx * aw;
        float cy = acy + dy * ah;
        dw = fminf(fmaxf(dw, -4.0f), 4.0f);
        dh = fminf(fmaxf(dh, -4.0f), 4.0f);
        float w = aw * expf(dw);
        float h = ah * expf(dh);
        float x0 = cx - 0.5f * w, y0 = cy - 0.5f * h;
        float x1 = cx + 0.5f * w, y1 = cy + 0.5f * h;
        x0 = fminf(fmaxf(x0, 0.0f), IMGF);
        y0 = fminf(fmaxf(y0, 0.0f), IMGF);
        x1 = fminf(fmaxf(x1, 0.0f), IMGF);
        y1 = fminf(fmaxf(y1, 0.0f), IMGF);
        sbox[tid] = make_float4(x0, y0, x1, y1);
    }
    __syncthreads();

    // ---- suppression bitmask + greedy serial scan ----
    {
#pragma clang fp contract(off)
        float4 bi = sbox[tid];
        float areai = fmaxf(bi.z - bi.x, 0.0f) * fmaxf(bi.w - bi.y, 0.0f);
        unsigned long long m0 = 0, m1 = 0, m2 = 0, m3 = 0;
        for (int jx = tid + 1; jx < K_N; ++jx) {
            float4 bj = sbox[jx];
            float areaj = fmaxf(bj.z - bj.x, 0.0f) * fmaxf(bj.w - bj.y, 0.0f);
            float lx = fmaxf(bi.x, bj.x), ly = fmaxf(bi.y, bj.y);
            float rx = fminf(bi.z, bj.z), ry = fminf(bi.w, bj.w);
            float iw = fmaxf(rx - lx, 0.0f), ih = fmaxf(ry - ly, 0.0f);
            float inter = iw * ih;
            float uni = areai + areaj - inter;
            float iou = inter / fmaxf(uni, 1e-8f);
            if (iou > IOU_T) {
                unsigned long long bit = 1ull << (jx & 63);
                switch (jx >> 6) {
                    case 0: m0 |= bit; break;
                    case 1: m1 |= bit; break;
                    case 2: m2 |= bit; break;
                    default: m3 |= bit; break;
                }
            }
        }
        supr[tid][0] = m0; supr[tid][1] = m1; supr[tid][2] = m2; supr[tid][3] = m3;
    }
    unsigned long long ball = __ballot(sscore[tid] > 0.0f);  // keep0 = s > 0
    if ((tid & 63) == 0) keepw[tid >> 6] = ball;
    __syncthreads();
    if (tid == 0) {
        unsigned long long k0 = keepw[0], k1 = keepw[1], k2 = keepw[2], k3 = keepw[3];
        for (int i = 0; i < K_N; ++i) {
            unsigned long long kw = (i < 64) ? k0 : (i < 128) ? k1 : (i < 192) ? k2 : k3;
            if ((kw >> (i & 63)) & 1ull) {
                k0 &= ~supr[i][0]; k1 &= ~supr[i][1];
                k2 &= ~supr[i][2]; k3 &= ~supr[i][3];
            }
        }
        keepw[0] = k0; keepw[1] = k1; keepw[2] = k2; keepw[3] = k3;
    }
    __syncthreads();

    // ---- outputs: dets [B,K,5] ++ labels [B,K] ++ keep [B,K] ----
    {
        float keepf = ((keepw[tid >> 6] >> (tid & 63)) & 1ull) ? 1.0f : 0.0f;
        float4 bx = sbox[tid];
        float s = sscore[tid];
        float* det = out + ((size_t)b * K_N + tid) * 5;
        det[0] = bx.x * keepf;
        det[1] = bx.y * keepf;
        det[2] = bx.z * keepf;
        det[3] = bx.w * keepf;
        det[4] = s * keepf;
        out[(size_t)B_N * K_N * 5 + (size_t)b * K_N + tid] = (float)slab[tid];
        out[(size_t)B_N * K_N * 5 + (size_t)B_N * K_N + (size_t)b * K_N + tid] = keepf;
    }
}

extern "C" void kernel_launch(void* const* d_in, const int* in_sizes, int n_in,
                              void* d_out, int out_size, void* d_ws, size_t ws_size,
                              hipStream_t stream)
{
    const float* logits  = (const float*)d_in[0];   // [B,A,C] fp32
    const float* regs    = (const float*)d_in[1];   // [B,A,4] fp32
    const float* anchors = (const float*)d_in[2];   // [A,4]   fp32
    float* out = (float*)d_out;

    // workspace layout (all 8B-aligned)
    uint32_t* keys   = (uint32_t*)d_ws;                                  // B*A u32
    int*      labels = (int*)(keys + (size_t)B_N * A_N);                 // B*A i32
    uint32_t* hist   = (uint32_t*)(labels + (size_t)B_N * A_N);          // B*NBIN u32
    uint32_t* counts = hist + (size_t)B_N * NBIN;                        // B u32
    unsigned long long* cand = (unsigned long long*)(counts + 8);        // B*CAP u64

    hipMemsetAsync(hist, 0, ((size_t)B_N * NBIN + 8) * sizeof(uint32_t), stream);

    const int total = B_N * A_N;                 // 392832 = 6138 * 64
    score_kernel<<<total / 64, 256, 0, stream>>>(logits, keys, labels);
    hist_kernel<<<dim3(16, B_N), 256, 0, stream>>>(keys, hist);
    compact_kernel<<<dim3(48, B_N), 256, 0, stream>>>(keys, hist, cand, counts);
    sort_nms_kernel<<<B_N, 256, 0, stream>>>(cand, counts, labels, regs, anchors, out);
}

// Round 4
// 239.500 us; speedup vs baseline: 1.9535x; 1.1787x over previous
//
#include <hip/hip_runtime.h>
#include <stdint.h>
#include <math.h>

// Problem constants (match reference setup_inputs)
#define IMGF   512.0f
#define A_N    49104
#define B_N    8
#define C_N    80
#define K_N    256
#define IOU_T  0.5f
#define NBIN   16384     // bin = key >> 16; max key 0x3F800000 >> 16 = 0x3F80 < 16384
#define HSHIFT 16
#define CAP    2048      // per-batch candidate capacity (nc expected ~300)

// ---------------------------------------------------------------------------
// Kernel A: 4 lanes per anchor, TWO anchors per lane-group (g0, g0+16) for 2x
// in-flight load bytes. Each lane: 10 independent float4 loads (fully-consumed
// 64B lines). Packed (flipped-logit || ~label) u64 max via 2 shuffles.
// Lane j==0 writes order-preserving score key + label. No atomics.
// total anchors = 392832 = 3069 blocks * 128 anchors/block (exact).
// ---------------------------------------------------------------------------
__global__ __launch_bounds__(256) void score_kernel(
    const float* __restrict__ logits,
    uint32_t* __restrict__ keys,
    int* __restrict__ labels)
{
    const int tid  = threadIdx.x;
    const int wave = tid >> 6, lane = tid & 63;
    const int grp  = lane >> 2, j = lane & 3;
    const int g0 = blockIdx.x * 128 + wave * 32 + grp;   // anchors g0, g0+16

    const float4* p0 = (const float4*)(logits + (size_t)g0 * C_N);
    const float4* p1 = (const float4*)(logits + (size_t)(g0 + 16) * C_N);
    unsigned long long best0 = 0ull, best1 = 0ull;
#pragma unroll
    for (int k = 0; k < 5; ++k) {
        float4 v0 = p0[j + 4 * k];
        float4 v1 = p1[j + 4 * k];
        const int bl = (j + 4 * k) * 4;
        float a0[4] = { v0.x, v0.y, v0.z, v0.w };
        float a1[4] = { v1.x, v1.y, v1.z, v1.w };
#pragma unroll
        for (int q = 0; q < 4; ++q) {
            uint32_t b0 = __float_as_uint(a0[q]);
            uint32_t u0 = b0 ^ (0x80000000u | (uint32_t)((int32_t)b0 >> 31));
            unsigned long long pk0 = ((unsigned long long)u0 << 32)
                                   | (uint32_t)(~(uint32_t)(bl + q));
            if (pk0 > best0) best0 = pk0;
            uint32_t b1 = __float_as_uint(a1[q]);
            uint32_t u1 = b1 ^ (0x80000000u | (uint32_t)((int32_t)b1 >> 31));
            unsigned long long pk1 = ((unsigned long long)u1 << 32)
                                   | (uint32_t)(~(uint32_t)(bl + q));
            if (pk1 > best1) best1 = pk1;
        }
    }
    {
        unsigned long long o;
        o = __shfl_xor(best0, 1, 64); if (o > best0) best0 = o;
        o = __shfl_xor(best0, 2, 64); if (o > best0) best0 = o;
        o = __shfl_xor(best1, 1, 64); if (o > best1) best1 = o;
        o = __shfl_xor(best1, 2, 64); if (o > best1) best1 = o;
    }
    if (j == 0) {
        uint32_t u0  = (uint32_t)(best0 >> 32);
        uint32_t mb0 = (u0 & 0x80000000u) ? (u0 ^ 0x80000000u) : ~u0;
        float m0 = __uint_as_float(mb0);
        float s0 = 1.0f / (1.0f + expf(-m0));
        if (!(s0 > 0.01f)) s0 = 0.0f;
        keys[g0]   = __float_as_uint(s0);
        labels[g0] = (int)~((uint32_t)best0);

        uint32_t u1  = (uint32_t)(best1 >> 32);
        uint32_t mb1 = (u1 & 0x80000000u) ? (u1 ^ 0x80000000u) : ~u1;
        float m1 = __uint_as_float(mb1);
        float s1 = 1.0f / (1.0f + expf(-m1));
        if (!(s1 > 0.01f)) s1 = 0.0f;
        keys[g0 + 16]   = __float_as_uint(s1);
        labels[g0 + 16] = (int)~((uint32_t)best1);
    }
}

// ---------------------------------------------------------------------------
// Kernel B (fused): one block (1024 threads) per batch.
//   1) LDS-private 16384-bin histogram of key>>16 (uint4 loads)
//   2) block suffix-scan -> exact threshold bin T (count(>T) < 256 <= count(>=T))
//   3) compact keys with bin >= T into LDS candidates (~300)
//   4) counting-rank sort by packed (key desc, idx asc) u64 == stable top_k
//   5) decode top-256 (fp-contract off), 256x256 suppression bitmask (1 word
//      per thread), branchless serial greedy scan == reference NMS
//   6) write dets [B,K,5] ++ labels [B,K] ++ keep [B,K] as float32
// ---------------------------------------------------------------------------
__global__ __launch_bounds__(1024) void select_nms_kernel(
    const uint32_t* __restrict__ keys,
    const int* __restrict__ labels,
    const float* __restrict__ regs,
    const float* __restrict__ anchors,
    float* __restrict__ out)
{
    const int b   = blockIdx.x;
    const int tid = threadIdx.x;          // 0..1023

    __shared__ uint32_t hist[NBIN];                 // 64 KB
    __shared__ int ssum[1024];                      // 4 KB
    __shared__ int sh_T, sh_nc;
    __shared__ unsigned long long cand[CAP];        // 16 KB
    __shared__ unsigned long long sorted[K_N];      // 2 KB
    __shared__ float4 sbox[K_N];
    __shared__ float  sscore[K_N];
    __shared__ int    slab[K_N];
    __shared__ unsigned long long supr[K_N][4];     // 8 KB
    __shared__ unsigned long long keepw[4];

    const uint32_t* kb = keys + (size_t)b * A_N;
    const uint4* kb4 = (const uint4*)kb;            // A_N % 4 == 0, 16B aligned
    const int N4 = A_N / 4;                         // 12276

    // ---- Phase 1: histogram ----
    for (int i = tid; i < NBIN; i += 1024) hist[i] = 0;
    __syncthreads();
    for (int i = tid; i < N4; i += 1024) {
        uint4 v = kb4[i];
        atomicAdd(&hist[v.x >> HSHIFT], 1u);
        atomicAdd(&hist[v.y >> HSHIFT], 1u);
        atomicAdd(&hist[v.z >> HSHIFT], 1u);
        atomicAdd(&hist[v.w >> HSHIFT], 1u);
    }
    __syncthreads();

    // ---- Phase 2: threshold bin via suffix scan ----
    const int lo = tid * (NBIN / 1024);             // 16 bins/thread
    int seg = 0;
#pragma unroll
    for (int q = 0; q < NBIN / 1024; ++q) seg += (int)hist[lo + q];
    ssum[tid] = seg;
    __syncthreads();
    for (int off = 1; off < 1024; off <<= 1) {      // inclusive suffix sum
        int v = (tid + off < 1024) ? ssum[tid + off] : 0;
        __syncthreads();
        ssum[tid] += v;
        __syncthreads();
    }
    int above = ssum[tid] - seg;                    // strictly-higher segments
    if (above < K_N && above + seg >= K_N) {        // exactly one thread true
        int cum = above;
        for (int bin = lo + NBIN / 1024 - 1; bin >= lo; --bin) {
            int c = (int)hist[bin];
            if (cum + c >= K_N) { sh_T = bin; break; }
            cum += c;
        }
    }
    if (tid == 0) sh_nc = 0;
    __syncthreads();
    const uint32_t T = (uint32_t)sh_T;

    // ---- Phase 3: compact candidates (bin >= T) ----
    for (int i = tid; i < N4; i += 1024) {
        uint4 v = kb4[i];
        uint32_t ks[4] = { v.x, v.y, v.z, v.w };
#pragma unroll
        for (int q = 0; q < 4; ++q) {
            if ((ks[q] >> HSHIFT) >= T) {
                int p = atomicAdd(&sh_nc, 1);
                if (p < CAP)
                    cand[p] = ((unsigned long long)ks[q] << 32)
                            | (unsigned long long)(0xFFFFFFFFu - (uint32_t)(4 * i + q));
            }
        }
    }
    if (tid < K_N) sorted[tid] = 0ull;
    __syncthreads();
    int nc = sh_nc; if (nc > CAP) nc = CAP;

    // ---- Phase 4: counting-rank sort (broadcast reads, no barriers) ----
    for (int i = tid; i < nc; i += 1024) {
        unsigned long long me = cand[i];
        int r = 0;
        for (int jq = 0; jq < nc; ++jq) r += (cand[jq] > me);
        if (r < K_N) sorted[r] = me;
    }
    __syncthreads();

    // ---- Phase 5: decode top-256 boxes (threads 0..255) ----
    if (tid < K_N) {
#pragma clang fp contract(off)
        unsigned long long cv = sorted[tid];
        uint32_t key = (uint32_t)(cv >> 32);
        uint32_t ai  = 0xFFFFFFFFu - (uint32_t)cv;
        if (ai >= (uint32_t)A_N) ai = 0;   // pad entries (score 0, unkept)
        int a = (int)ai;
        float s = __uint_as_float(key);
        sscore[tid] = s;
        slab[tid]   = labels[(size_t)b * A_N + a];

        float ax0 = anchors[4 * a + 0], ay0 = anchors[4 * a + 1];
        float ax1 = anchors[4 * a + 2], ay1 = anchors[4 * a + 3];
        float aw = ax1 - ax0, ah = ay1 - ay0;
        float acx = ax0 + 0.5f * aw, acy = ay0 + 0.5f * ah;
        const float* r = regs + ((size_t)b * A_N + a) * 4;
        float dx = r[0], dy = r[1], dw = r[2], dh = r[3];
        float cx = acx + dx * aw;
        float cy = acy + dy * ah;
        dw = fminf(fmaxf(dw, -4.0f), 4.0f);
        dh = fminf(fmaxf(dh, -4.0f), 4.0f);
        float w = aw * expf(dw);
        float h = ah * expf(dh);
        float x0 = cx - 0.5f * w, y0 = cy - 0.5f * h;
        float x1 = cx + 0.5f * w, y1 = cy + 0.5f * h;
        x0 = fminf(fmaxf(x0, 0.0f), IMGF);
        y0 = fminf(fmaxf(y0, 0.0f), IMGF);
        x1 = fminf(fmaxf(x1, 0.0f), IMGF);
        y1 = fminf(fmaxf(y1, 0.0f), IMGF);
        sbox[tid] = make_float4(x0, y0, x1, y1);
    }
    __syncthreads();

    // ---- Phase 6a: suppression matrix, one u64 word per thread ----
    {
#pragma clang fp contract(off)
        const int row = tid & 255, gq = tid >> 8;   // word gq of row
        float4 bi = sbox[row];
        float areai = fmaxf(bi.z - bi.x, 0.0f) * fmaxf(bi.w - bi.y, 0.0f);
        unsigned long long m = 0;
        const int jlo = gq * 64, jhi = jlo + 64;
        int start = row + 1 > jlo ? row + 1 : jlo;
        for (int jx = start; jx < jhi; ++jx) {
            float4 bj = sbox[jx];
            float areaj = fmaxf(bj.z - bj.x, 0.0f) * fmaxf(bj.w - bj.y, 0.0f);
            float lx = fmaxf(bi.x, bj.x), ly = fmaxf(bi.y, bj.y);
            float rx = fminf(bi.z, bj.z), ry = fminf(bi.w, bj.w);
            float iw = fmaxf(rx - lx, 0.0f), ih = fmaxf(ry - ly, 0.0f);
            float inter = iw * ih;
            float uni = areai + areaj - inter;
            float iou = inter / fmaxf(uni, 1e-8f);
            if (iou > IOU_T) m |= 1ull << (jx & 63);
        }
        supr[row][gq] = m;
    }
    // keep0 = score > 0 (threads 0..255 = waves 0..3)
    if (tid < K_N) {
        unsigned long long ball = __ballot(sscore[tid] > 0.0f);
        if ((tid & 63) == 0) keepw[tid >> 6] = ball;
    }
    __syncthreads();

    // ---- Phase 6b: branchless serial greedy scan (loads hoisted) ----
    if (tid == 0) {
        unsigned long long k0 = keepw[0], k1 = keepw[1], k2 = keepw[2], k3 = keepw[3];
#define NMS_CHUNK(c, kc)                                                     \
        for (int l = 0; l < 64; ++l) {                                       \
            const int i = (c) * 64 + l;                                      \
            unsigned long long w0 = supr[i][0], w1 = supr[i][1];             \
            unsigned long long w2 = supr[i][2], w3 = supr[i][3];             \
            if ((kc >> l) & 1ull) {                                          \
                k0 &= ~w0; k1 &= ~w1; k2 &= ~w2; k3 &= ~w3;                  \
            }                                                                \
        }
        NMS_CHUNK(0, k0)
        NMS_CHUNK(1, k1)
        NMS_CHUNK(2, k2)
        NMS_CHUNK(3, k3)
#undef NMS_CHUNK
        keepw[0] = k0; keepw[1] = k1; keepw[2] = k2; keepw[3] = k3;
    }
    __syncthreads();

    // ---- Phase 7: outputs: dets [B,K,5] ++ labels [B,K] ++ keep [B,K] ----
    if (tid < K_N) {
        float keepf = ((keepw[tid >> 6] >> (tid & 63)) & 1ull) ? 1.0f : 0.0f;
        float4 bx = sbox[tid];
        float s = sscore[tid];
        float* det = out + ((size_t)b * K_N + tid) * 5;
        det[0] = bx.x * keepf;
        det[1] = bx.y * keepf;
        det[2] = bx.z * keepf;
        det[3] = bx.w * keepf;
        det[4] = s * keepf;
        out[(size_t)B_N * K_N * 5 + (size_t)b * K_N + tid] = (float)slab[tid];
        out[(size_t)B_N * K_N * 5 + (size_t)B_N * K_N + (size_t)b * K_N + tid] = keepf;
    }
}

extern "C" void kernel_launch(void* const* d_in, const int* in_sizes, int n_in,
                              void* d_out, int out_size, void* d_ws, size_t ws_size,
                              hipStream_t stream)
{
    const float* logits  = (const float*)d_in[0];   // [B,A,C] fp32
    const float* regs    = (const float*)d_in[1];   // [B,A,4] fp32
    const float* anchors = (const float*)d_in[2];   // [A,4]   fp32
    float* out = (float*)d_out;

    uint32_t* keys   = (uint32_t*)d_ws;                      // B*A u32
    int*      labels = (int*)(keys + (size_t)B_N * A_N);     // B*A i32

    const int total = B_N * A_N;                 // 392832 = 3069 * 128
    score_kernel<<<total / 128, 256, 0, stream>>>(logits, keys, labels);
    select_nms_kernel<<<B_N, 1024, 0, stream>>>(keys, labels, regs, anchors, out);
}